// Round 3
// baseline (180.935 us; speedup 1.0000x reference)
//
#include <hip/hip_runtime.h>
#include <hip/hip_bf16.h>

typedef __bf16 bf16;
typedef bf16  bf16x4 __attribute__((ext_vector_type(4)));
typedef bf16  bf16x8 __attribute__((ext_vector_type(8)));
typedef float f32x4  __attribute__((ext_vector_type(4)));

union B8 { bf16x8 v; bf16 e[8]; };
union B4 { bf16x4 v; bf16 e[4]; };
union F4 { f32x4 v; float e[4]; };

// Async global->LDS DMA, 16 B per lane (wave-uniform LDS base, lane i ->
// base + i*16).
#define GLOAD_LDS16(g, l)                                            \
  __builtin_amdgcn_global_load_lds(                                  \
      (const __attribute__((address_space(1))) void*)(g),            \
      (__attribute__((address_space(3))) void*)(l), 16, 0, 0)

// Swizzled tile: row stride 64 bf16, 16B chunk p = c8 ^ (row & 7).
#define SWZ(arr, R, c8) (*(const bf16x8*)&(arr)[(size_t)(R) * 64 + (((c8) ^ ((R) & 7)) << 3)])

// ---------------------------------------------------------------------------
// Kernel 0: weight conversion fp32 -> bf16. q/k rows scaled by
// 0.35355339 * sqrt(log2(e)) = 0.42468158 -> scores arrive in log2 domain.
// ---------------------------------------------------------------------------
__global__ __launch_bounds__(256) void conv_w_kernel(
    const float* __restrict__ qkvw, const float* __restrict__ qkvb,
    const float* __restrict__ pw,
    bf16* __restrict__ Wb, bf16* __restrict__ Pb, float* __restrict__ bs)
{
  const int row = blockIdx.x;
  const int tid = threadIdx.x;
  if (row < 3072) {
    const float s = ((row % 192) < 128) ? 0.42468158f : 1.0f;
    const float4 a = ((const float4*)(qkvw + (size_t)row * 1024))[tid];
    B4 o;
    o.e[0] = (bf16)(a.x * s); o.e[1] = (bf16)(a.y * s);
    o.e[2] = (bf16)(a.z * s); o.e[3] = (bf16)(a.w * s);
    ((bf16x4*)(Wb + (size_t)row * 1024))[tid] = o.v;
    if (tid == 0) bs[row] = qkvb[row] * s;
  } else {
    const int r = row - 3072;
    const float4 a = ((const float4*)(pw + (size_t)r * 1024))[tid];
    B4 o;
    o.e[0] = (bf16)a.x; o.e[1] = (bf16)a.y;
    o.e[2] = (bf16)a.z; o.e[3] = (bf16)a.w;
    ((bf16x4*)(Pb + (size_t)r * 1024))[tid] = o.v;
  }
}

// ---------------------------------------------------------------------------
// Kernel 1: GroupNorm, transposed output: x[b][c][t] fp32 -> xnt[b][t][c] bf16.
// 256 blocks (2 per (b,g) group; was 128 = half the chip idle). Both halves
// redundantly compute stats (128 KB re-read, L2/L3-resident); each block
// normalizes half the t-range.
// ---------------------------------------------------------------------------
__global__ __launch_bounds__(256) void gn_t_kernel(
    const float* __restrict__ x, const float* __restrict__ w,
    const float* __restrict__ bias, bf16* __restrict__ xnt)
{
  const int blk = blockIdx.x;
  const int b = blk >> 6, g = (blk >> 1) & 31, half = blk & 1;
  const float* xp = x + (size_t)(b * 1024 + g * 32) * 1024;
  const int tid = threadIdx.x;

  float s = 0.f, ss = 0.f;
  for (int ch = tid; ch < 4096; ch += 256) {
    const float4* p = (const float4*)(xp + (size_t)ch * 8);
    float4 u0 = p[0], u1 = p[1];
    s  += u0.x + u0.y + u0.z + u0.w + u1.x + u1.y + u1.z + u1.w;
    ss += u0.x*u0.x + u0.y*u0.y + u0.z*u0.z + u0.w*u0.w
        + u1.x*u1.x + u1.y*u1.y + u1.z*u1.z + u1.w*u1.w;
  }
  #pragma unroll
  for (int m = 1; m < 64; m <<= 1) { s += __shfl_xor(s, m); ss += __shfl_xor(ss, m); }

  __shared__ float red[8];
  __shared__ float stats[2];
  const int wave = tid >> 6, lane = tid & 63;
  if (lane == 0) { red[wave] = s; red[4 + wave] = ss; }
  __syncthreads();
  if (tid == 0) {
    float ts  = red[0] + red[1] + red[2] + red[3];
    float tss = red[4] + red[5] + red[6] + red[7];
    float mu  = ts * (1.f / 32768.f);
    float var = tss * (1.f / 32768.f) - mu * mu;
    stats[0] = mu;
    stats[1] = rsqrtf(var + 1e-5f);
  }
  __syncthreads();
  const float mu = stats[0], rs = stats[1];

  for (int ti = half * 2; ti < half * 2 + 2; ++ti) {
    const int t = ti * 256 + tid;
    B8 o[4];
    #pragma unroll
    for (int cc = 0; cc < 32; ++cc) {
      const float wt = w[g * 32 + cc] * rs;
      const float bsv = bias[g * 32 + cc];
      const float v = xp[(size_t)cc * 1024 + t];
      o[cc >> 3].e[cc & 7] = (bf16)((v - mu) * wt + bsv);
    }
    bf16* dst = xnt + (size_t)(b * 1024 + t) * 1024 + g * 32;
    #pragma unroll
    for (int j = 0; j < 4; ++j) *(bf16x8*)(dst + j * 8) = o[j].v;
  }
}

// ---------------------------------------------------------------------------
// Kernel 2: merged qkv GEMM. Tile 256x192 -> grid 256 blocks = 1/CU.
// Minimal 2-phase pipeline: all ds_reads of the current buffer first, then
// next tile's 7 global_load_lds into buf^1, then 48 MFMAs, one __syncthreads
// per K-tile. 8 waves (2M x 4N), wave tile 128x48. Each N-tile (192 cols)
// = one head group -> uniform epilogue. LDS 112 KB.
// ---------------------------------------------------------------------------
__global__ __launch_bounds__(512, 2) void gemm_qkv_kernel(
    const bf16* __restrict__ xnt, const bf16* __restrict__ Wb,
    const float* __restrict__ bs, bf16* __restrict__ qkT, bf16* __restrict__ vv)
{
  const int bid = blockIdx.x;
  const int swz = (bid & 7) * 32 + (bid >> 3);   // bijective: 256 = 8 * 32
  const int bxn = swz >> 4, bym = swz & 15;      // per XCD: 2 N-panels x 16 M
  const int n0 = bxn * 192, m0 = bym * 256;
  const int head = bxn;

  __shared__ __align__(16) bf16 Al[2][256 * 64];
  __shared__ __align__(16) bf16 Bl[2][192 * 64];

  const int tid  = threadIdx.x;
  const int wave = tid >> 6, lane = tid & 63;
  const int quad = lane >> 4, l15 = lane & 15;
  const int wr = wave >> 2, wc = wave & 3;
  const int lrow = lane >> 3, lp = lane & 7;
  const int sc8 = (lp ^ lrow) << 3;   // pre-swizzled source chunk (elements)

  #define STAGE(bufn, kt) do {                                                \
    _Pragma("unroll")                                                         \
    for (int c = 0; c < 4; ++c)                                               \
      GLOAD_LDS16(xnt + (size_t)(m0 + c * 64 + wave * 8 + lrow) * 1024 +      \
                      (size_t)(kt) * 64 + sc8,                                \
                  &Al[bufn][(c * 64 + wave * 8) * 64]);                       \
    _Pragma("unroll")                                                         \
    for (int c = 0; c < 3; ++c)                                               \
      GLOAD_LDS16(Wb + (size_t)(n0 + c * 64 + wave * 8 + lrow) * 1024 +       \
                      (size_t)(kt) * 64 + sc8,                                \
                  &Bl[bufn][(c * 64 + wave * 8) * 64]);                       \
  } while (0)

  F4 acc[8][3];
  #pragma unroll
  for (int i = 0; i < 8; ++i)
    #pragma unroll
    for (int j = 0; j < 3; ++j) acc[i][j].v = (f32x4){0.f, 0.f, 0.f, 0.f};

  STAGE(0, 0);
  __syncthreads();

  for (int t = 0; t < 16; ++t) {
    const int cb = t & 1;

    bf16x8 af[2][8], bfr[2][3];
    #pragma unroll
    for (int kk = 0; kk < 2; ++kk) {
      #pragma unroll
      for (int nt = 0; nt < 3; ++nt)
        bfr[kk][nt] = SWZ(Bl[cb], wc * 48 + nt * 16 + l15, kk * 4 + quad);
      #pragma unroll
      for (int mt = 0; mt < 8; ++mt)
        af[kk][mt] = SWZ(Al[cb], wr * 128 + mt * 16 + l15, kk * 4 + quad);
    }

    if (t + 1 < 16) STAGE(cb ^ 1, t + 1);

    #pragma unroll
    for (int kk = 0; kk < 2; ++kk)
      #pragma unroll
      for (int mt = 0; mt < 8; ++mt)
        #pragma unroll
        for (int nt = 0; nt < 3; ++nt)
          acc[mt][nt].v = __builtin_amdgcn_mfma_f32_16x16x32_bf16(
              af[kk][mt], bfr[kk][nt], acc[mt][nt].v, 0, 0, 0);

    __syncthreads();
  }
  #undef STAGE

  const int z  = m0 >> 10;
  const int tb = (m0 & 1023) + wr * 128;
  #pragma unroll
  for (int nt = 0; nt < 3; ++nt) {
    const int r192 = wc * 48 + nt * 16;     // 0..176, wave-uniform
    const float bb = bs[n0 + r192 + l15];
    if (r192 < 128) {
      const int col = head * 128 + r192 + l15;
      #pragma unroll
      for (int mt = 0; mt < 8; ++mt)
        #pragma unroll
        for (int r = 0; r < 4; ++r) {
          const int m = m0 + wr * 128 + mt * 16 + quad * 4 + r;
          qkT[(size_t)m * 2048 + col] = (bf16)(acc[mt][nt].e[r] + bb);
        }
    } else {
      bf16* vrow = vv + ((size_t)z * 1024 + head * 64 + (r192 - 128) + l15) * 1024;
      #pragma unroll
      for (int mt = 0; mt < 8; ++mt) {
        B4 pk;
        #pragma unroll
        for (int r = 0; r < 4; ++r) pk.e[r] = (bf16)(acc[mt][nt].e[r] + bb);
        *(bf16x4*)&vrow[tb + mt * 16 + quad * 4] = pk.v;
      }
    }
  }
}

// ---------------------------------------------------------------------------
// Kernel 4: proj GEMM v2. z fused into the t-dim (at is contiguous
// [b*t][c]): one GEMM M=1024 (channels, Pb rows) x N=4096 (t) x K=1024.
// Tile 128x128 -> grid 8x32 = 256 blocks = 1/CU (was 1024 64^2 blocks with
// 4 MFMA per sync pair). Same 2-phase pipeline as qkv: ds_reads first,
// prefetch next K-tile, 16 MFMA/wave, one barrier. 8 waves (2m x 4n),
// wave tile 64(m) x 32(n). LDS 64 KB. out = acc + bias + residual (fp32).
// Operand roles & K order identical to old proj -> same numerics.
// ---------------------------------------------------------------------------
__global__ __launch_bounds__(512, 2) void gemm_proj_kernel(
    const bf16* __restrict__ Pb, const bf16* __restrict__ Bt,
    float* __restrict__ out, const float* __restrict__ bias,
    const float* __restrict__ resf)
{
  const int bid = blockIdx.x;
  const int swz = (bid & 7) * 32 + (bid >> 3);   // bijective: 256 = 8 * 32
  const int mp = swz & 7, np = swz >> 3;
  const int m0 = mp * 128;                       // channel base
  const int n0g = np * 128;                      // global t base (b*1024+t)

  __shared__ __align__(16) bf16 Al[2][128 * 64]; // Pb rows (m)
  __shared__ __align__(16) bf16 Bl[2][128 * 64]; // at rows (n)

  const int tid  = threadIdx.x;
  const int wave = tid >> 6, lane = tid & 63;
  const int quad = lane >> 4, l15 = lane & 15;
  const int wr = wave >> 2, wc = wave & 3;       // 2(m) x 4(n)
  const int lrow = lane >> 3, lp = lane & 7;
  const int sc8 = (lp ^ lrow) << 3;

  #define STAGE(bufn, kt) do {                                                \
    _Pragma("unroll")                                                         \
    for (int c = 0; c < 2; ++c)                                               \
      GLOAD_LDS16(Pb + (size_t)(m0 + c * 64 + wave * 8 + lrow) * 1024 +       \
                      (size_t)(kt) * 64 + sc8,                                \
                  &Al[bufn][(c * 64 + wave * 8) * 64]);                       \
    _Pragma("unroll")                                                         \
    for (int c = 0; c < 2; ++c)                                               \
      GLOAD_LDS16(Bt + (size_t)(n0g + c * 64 + wave * 8 + lrow) * 1024 +      \
                      (size_t)(kt) * 64 + sc8,                                \
                  &Bl[bufn][(c * 64 + wave * 8) * 64]);                       \
  } while (0)

  F4 acc[4][2];
  #pragma unroll
  for (int i = 0; i < 4; ++i)
    #pragma unroll
    for (int j = 0; j < 2; ++j) acc[i][j].v = (f32x4){0.f, 0.f, 0.f, 0.f};

  STAGE(0, 0);
  __syncthreads();

  for (int t = 0; t < 16; ++t) {
    const int cb = t & 1;

    bf16x8 af[2][4], bfr[2][2];
    #pragma unroll
    for (int kk = 0; kk < 2; ++kk) {
      #pragma unroll
      for (int mt = 0; mt < 4; ++mt)
        af[kk][mt] = SWZ(Al[cb], wr * 64 + mt * 16 + l15, kk * 4 + quad);
      #pragma unroll
      for (int nt = 0; nt < 2; ++nt)
        bfr[kk][nt] = SWZ(Bl[cb], wc * 32 + nt * 16 + l15, kk * 4 + quad);
    }

    if (t + 1 < 16) STAGE(cb ^ 1, t + 1);

    #pragma unroll
    for (int kk = 0; kk < 2; ++kk)
      #pragma unroll
      for (int mt = 0; mt < 4; ++mt)
        #pragma unroll
        for (int nt = 0; nt < 2; ++nt)
          acc[mt][nt].v = __builtin_amdgcn_mfma_f32_16x16x32_bf16(
              af[kk][mt], bfr[kk][nt], acc[mt][nt].v, 0, 0, 0);

    __syncthreads();
  }
  #undef STAGE

  const int z  = n0g >> 10;                 // block-uniform (128 | 1024)
  const int nl = n0g & 1023;
  const size_t zoff = (size_t)z * 1024 * 1024;
  #pragma unroll
  for (int mt = 0; mt < 4; ++mt) {
    #pragma unroll
    for (int r = 0; r < 4; ++r) {
      const int m = m0 + wr * 64 + mt * 16 + quad * 4 + r;
      const float bb = bias[m];
      #pragma unroll
      for (int nt = 0; nt < 2; ++nt) {
        const int n = nl + wc * 32 + nt * 16 + l15;
        out[zoff + (size_t)m * 1024 + n] =
            acc[mt][nt].e[r] + bb + resf[zoff + (size_t)m * 1024 + n];
      }
    }
  }
}

// ---------------------------------------------------------------------------
// Kernel 3: attention, S^T + no-max softmax, 128-t blocks: each wave owns
// TWO independent 16-t bands -> k/v fragments read ONCE per wave-chunk and
// reused by both bands, two independent S->exp->PV chains interleave for
// latency hiding, k/v staged per 128 t. grid (16,8,4) = 512 blocks.
// LDS: qP 16K (q then P bands) + kl 2x8K + vl 2x8K = 48 KB.
// ---------------------------------------------------------------------------
__global__ __launch_bounds__(256) void attn_kernel(
    const bf16* __restrict__ qkTin, const bf16* __restrict__ vmat,
    bf16* __restrict__ aout)
{
  const int h = blockIdx.x, tt = blockIdx.y, z = blockIdx.z;
  const bf16* qk = qkTin + (size_t)z * 1024 * 2048;
  const bf16* vp = vmat + (size_t)z * 1024 * 1024 + (size_t)(h * 64) * 1024;
  aout += (size_t)z * 1024 * 1024;
  const int t0 = tt * 128;

  __shared__ __align__(16) bf16 qP[128 * 64];     // q rows (init) then P bands
  __shared__ __align__(16) bf16 kl[2][64 * 64];
  __shared__ __align__(16) bf16 vl[2][64 * 64];

  const int tid  = threadIdx.x;
  const int wave = tid >> 6, lane = tid & 63;
  const int quad = lane >> 4, l15 = lane & 15;
  const int lrow = lane >> 3, lp = lane & 7;

  #pragma unroll
  for (int c = 0; c < 4; ++c) {
    const int row = wave * 32 + c * 8 + lrow;
    const int c8  = lp ^ (row & 7);
    GLOAD_LDS16(qk + (size_t)(t0 + row) * 2048 + h * 128 + c8 * 8,
                &qP[(wave * 32 + c * 8) * 64]);
  }
  const int r0 = wave * 16 + lrow, r1 = wave * 16 + 8 + lrow;
  const int c80 = lp ^ (r0 & 7), c81 = lp ^ (r1 & 7);
  GLOAD_LDS16(qk + (size_t)r0 * 2048 + h * 128 + 64 + c80 * 8, &kl[0][(wave * 16) * 64]);
  GLOAD_LDS16(qk + (size_t)r1 * 2048 + h * 128 + 64 + c81 * 8, &kl[0][(wave * 16 + 8) * 64]);
  GLOAD_LDS16(vp + (size_t)r0 * 1024 + c80 * 8, &vl[0][(wave * 16) * 64]);
  GLOAD_LDS16(vp + (size_t)r1 * 1024 + c81 * 8, &vl[0][(wave * 16 + 8) * 64]);
  __syncthreads();

  bf16x8 bq0[2], bq1[2];
  int prow[2];
  #pragma unroll
  for (int b = 0; b < 2; ++b) {
    const int Rq = wave * 32 + b * 16 + l15;
    bq0[b] = SWZ(qP, Rq, quad);
    bq1[b] = SWZ(qP, Rq, quad + 4);
    prow[b] = Rq;
  }

  float l_i[2] = {0.f, 0.f};
  F4 oacc[2][4];
  #pragma unroll
  for (int b = 0; b < 2; ++b)
    #pragma unroll
    for (int ct = 0; ct < 4; ++ct) oacc[b][ct].v = (f32x4){0.f, 0.f, 0.f, 0.f};

  const int pq8 = (quad & 1) * 4;

  int buf = 0;
  for (int s0 = 0; s0 < 1024; s0 += 64) {
    if (s0 + 64 < 1024) {
      const int nb = buf ^ 1, sn = s0 + 64;
      GLOAD_LDS16(qk + (size_t)(sn + r0) * 2048 + h * 128 + 64 + c80 * 8,
                  &kl[nb][(wave * 16) * 64]);
      GLOAD_LDS16(qk + (size_t)(sn + r1) * 2048 + h * 128 + 64 + c81 * 8,
                  &kl[nb][(wave * 16 + 8) * 64]);
      GLOAD_LDS16(vp + (size_t)r0 * 1024 + sn + c80 * 8, &vl[nb][(wave * 16) * 64]);
      GLOAD_LDS16(vp + (size_t)r1 * 1024 + sn + c81 * 8, &vl[nb][(wave * 16 + 8) * 64]);
    }

    bf16x8 ak0[4], ak1[4], bv[2][4];
    #pragma unroll
    for (int st = 0; st < 4; ++st) {
      const int Rk = st * 16 + l15;
      ak0[st] = SWZ(kl[buf], Rk, quad);
      ak1[st] = SWZ(kl[buf], Rk, quad + 4);
    }
    #pragma unroll
    for (int ks = 0; ks < 2; ++ks)
      #pragma unroll
      for (int ct = 0; ct < 4; ++ct)
        bv[ks][ct] = SWZ(vl[buf], ct * 16 + l15, ks * 4 + quad);

    #pragma unroll
    for (int b = 0; b < 2; ++b) {
      F4 sacc[4];
      #pragma unroll
      for (int st = 0; st < 4; ++st) sacc[st].v = (f32x4){0.f, 0.f, 0.f, 0.f};
      #pragma unroll
      for (int st = 0; st < 4; ++st) {
        sacc[st].v = __builtin_amdgcn_mfma_f32_16x16x32_bf16(ak0[st], bq0[b], sacc[st].v, 0, 0, 0);
        sacc[st].v = __builtin_amdgcn_mfma_f32_16x16x32_bf16(ak1[st], bq1[b], sacc[st].v, 0, 0, 0);
      }

      bf16* const pbase = &qP[(size_t)prow[b] * 64];
      #pragma unroll
      for (int st = 0; st < 4; ++st) {
        B4 pk;
        #pragma unroll
        for (int r = 0; r < 4; ++r) {
          const float p = __builtin_amdgcn_exp2f(sacc[st].e[r]);
          l_i[b] += p;
          pk.e[r] = (bf16)p;
        }
        const int c8 = (st * 2 + (quad >> 1)) ^ (prow[b] & 7);
        *(bf16x4*)(pbase + (c8 << 3) + pq8) = pk.v;
      }

      #pragma unroll
      for (int ks = 0; ks < 2; ++ks) {
        const bf16x8 ap = SWZ(qP, prow[b], ks * 4 + quad);
        #pragma unroll
        for (int ct = 0; ct < 4; ++ct)
          oacc[b][ct].v = __builtin_amdgcn_mfma_f32_16x16x32_bf16(
              ap, bv[ks][ct], oacc[b][ct].v, 0, 0, 0);
      }
    }
    __syncthreads();
    buf ^= 1;
  }

  #pragma unroll
  for (int b = 0; b < 2; ++b) {
    float li = l_i[b];
    li += __shfl_xor(li, 16);
    li += __shfl_xor(li, 32);
    const float inv = 1.f / li;
    float iv[4];
    #pragma unroll
    for (int r = 0; r < 4; ++r) iv[r] = __shfl(inv, quad * 4 + r);
    #pragma unroll
    for (int r = 0; r < 4; ++r) {
      const int t = t0 + wave * 32 + b * 16 + quad * 4 + r;
      #pragma unroll
      for (int ct = 0; ct < 4; ++ct)
        aout[(size_t)t * 1024 + h * 64 + ct * 16 + l15] = (bf16)(oacc[b][ct].e[r] * iv[r]);
    }
  }
}

// ---------------------------------------------------------------------------
// ws layout:
//   xnt [b][t][c] : ws[ 0,  8 MB)
//   qkT [b][t][n] : ws[ 8, 24 MB)
//   v   [b][ov][t]: ws[24, 32 MB)
//   a^T [b][t][c] : ws[32, 40 MB)
//   Wb / Pb / bs  : ws[40, 48 MB) + 12 KB
// ---------------------------------------------------------------------------
extern "C" void kernel_launch(void* const* d_in, const int* in_sizes, int n_in,
                              void* d_out, int out_size, void* d_ws, size_t ws_size,
                              hipStream_t stream)
{
  const float* x    = (const float*)d_in[0];
  const float* nw   = (const float*)d_in[1];
  const float* nb   = (const float*)d_in[2];
  const float* qkvw = (const float*)d_in[3];
  const float* qkvb = (const float*)d_in[4];
  const float* pw   = (const float*)d_in[5];
  const float* pb   = (const float*)d_in[6];
  float* out = (float*)d_out;

  const long M1 = 1024L * 1024L;
  bf16*  xnt = (bf16*)d_ws;
  bf16*  qkT = xnt + 4 * M1;
  bf16*  vv  = xnt + 12 * M1;
  bf16*  at  = xnt + 16 * M1;
  bf16*  Wb  = xnt + 20 * M1;
  bf16*  Pb  = xnt + 23 * M1;
  float* bs  = (float*)(xnt + 24 * M1);

  conv_w_kernel<<<dim3(4096), dim3(256), 0, stream>>>(qkvw, qkvb, pw, Wb, Pb, bs);
  gn_t_kernel<<<dim3(256), dim3(256), 0, stream>>>(x, nw, nb, xnt);
  gemm_qkv_kernel<<<dim3(256), dim3(512), 0, stream>>>(xnt, Wb, bs, qkT, vv);
  attn_kernel<<<dim3(16, 8, 4), dim3(256), 0, stream>>>(qkT, vv, at);
  gemm_proj_kernel<<<dim3(256), dim3(512), 0, stream>>>(Pb, at, out, pb, x);
}

// Round 4
// 176.009 us; speedup vs baseline: 1.0280x; 1.0280x over previous
//
#include <hip/hip_runtime.h>
#include <hip/hip_bf16.h>

typedef __bf16 bf16;
typedef bf16  bf16x4 __attribute__((ext_vector_type(4)));
typedef bf16  bf16x8 __attribute__((ext_vector_type(8)));
typedef float f32x4  __attribute__((ext_vector_type(4)));

union B8 { bf16x8 v; bf16 e[8]; };
union B4 { bf16x4 v; bf16 e[4]; };
union F4 { f32x4 v; float e[4]; };

// Async global->LDS DMA, 16 B per lane (wave-uniform LDS base, lane i ->
// base + i*16).
#define GLOAD_LDS16(g, l)                                            \
  __builtin_amdgcn_global_load_lds(                                  \
      (const __attribute__((address_space(1))) void*)(g),            \
      (__attribute__((address_space(3))) void*)(l), 16, 0, 0)

// Swizzled tile: row stride 64 bf16, 16B chunk p = c8 ^ (row & 7).
#define SWZ(arr, R, c8) (*(const bf16x8*)&(arr)[(size_t)(R) * 64 + (((c8) ^ ((R) & 7)) << 3)])

// ---------------------------------------------------------------------------
// Kernel 0: weight conversion fp32 -> bf16. q/k rows scaled by
// 0.35355339 * sqrt(log2(e)) = 0.42468158 -> scores arrive in log2 domain.
// ---------------------------------------------------------------------------
__global__ __launch_bounds__(256) void conv_w_kernel(
    const float* __restrict__ qkvw, const float* __restrict__ qkvb,
    const float* __restrict__ pw,
    bf16* __restrict__ Wb, bf16* __restrict__ Pb, float* __restrict__ bs)
{
  const int row = blockIdx.x;
  const int tid = threadIdx.x;
  if (row < 3072) {
    const float s = ((row % 192) < 128) ? 0.42468158f : 1.0f;
    const float4 a = ((const float4*)(qkvw + (size_t)row * 1024))[tid];
    B4 o;
    o.e[0] = (bf16)(a.x * s); o.e[1] = (bf16)(a.y * s);
    o.e[2] = (bf16)(a.z * s); o.e[3] = (bf16)(a.w * s);
    ((bf16x4*)(Wb + (size_t)row * 1024))[tid] = o.v;
    if (tid == 0) bs[row] = qkvb[row] * s;
  } else {
    const int r = row - 3072;
    const float4 a = ((const float4*)(pw + (size_t)r * 1024))[tid];
    B4 o;
    o.e[0] = (bf16)a.x; o.e[1] = (bf16)a.y;
    o.e[2] = (bf16)a.z; o.e[3] = (bf16)a.w;
    ((bf16x4*)(Pb + (size_t)r * 1024))[tid] = o.v;
  }
}

// ---------------------------------------------------------------------------
// Kernel 1: GroupNorm, transposed output: x[b][c][t] fp32 -> xnt[b][t][c] bf16.
// (round-2 version: 128 blocks, one per (b,g) group)
// ---------------------------------------------------------------------------
__global__ __launch_bounds__(256) void gn_t_kernel(
    const float* __restrict__ x, const float* __restrict__ w,
    const float* __restrict__ bias, bf16* __restrict__ xnt)
{
  const int blk = blockIdx.x;
  const int b = blk >> 5, g = blk & 31;
  const float* xp = x + (size_t)(b * 1024 + g * 32) * 1024;
  const int tid = threadIdx.x;

  float s = 0.f, ss = 0.f;
  for (int ch = tid; ch < 4096; ch += 256) {
    const float4* p = (const float4*)(xp + (size_t)ch * 8);
    float4 u0 = p[0], u1 = p[1];
    s  += u0.x + u0.y + u0.z + u0.w + u1.x + u1.y + u1.z + u1.w;
    ss += u0.x*u0.x + u0.y*u0.y + u0.z*u0.z + u0.w*u0.w
        + u1.x*u1.x + u1.y*u1.y + u1.z*u1.z + u1.w*u1.w;
  }
  #pragma unroll
  for (int m = 1; m < 64; m <<= 1) { s += __shfl_xor(s, m); ss += __shfl_xor(ss, m); }

  __shared__ float red[8];
  __shared__ float stats[2];
  const int wave = tid >> 6, lane = tid & 63;
  if (lane == 0) { red[wave] = s; red[4 + wave] = ss; }
  __syncthreads();
  if (tid == 0) {
    float ts  = red[0] + red[1] + red[2] + red[3];
    float tss = red[4] + red[5] + red[6] + red[7];
    float mu  = ts * (1.f / 32768.f);
    float var = tss * (1.f / 32768.f) - mu * mu;
    stats[0] = mu;
    stats[1] = rsqrtf(var + 1e-5f);
  }
  __syncthreads();
  const float mu = stats[0], rs = stats[1];

  for (int ti = 0; ti < 4; ++ti) {
    const int t = ti * 256 + tid;
    B8 o[4];
    #pragma unroll
    for (int cc = 0; cc < 32; ++cc) {
      const float wt = w[g * 32 + cc] * rs;
      const float bsv = bias[g * 32 + cc];
      const float v = xp[(size_t)cc * 1024 + t];
      o[cc >> 3].e[cc & 7] = (bf16)((v - mu) * wt + bsv);
    }
    bf16* dst = xnt + (size_t)(b * 1024 + t) * 1024 + g * 32;
    #pragma unroll
    for (int j = 0; j < 4; ++j) *(bf16x8*)(dst + j * 8) = o[j].v;
  }
}

// ---------------------------------------------------------------------------
// Kernel 2: merged qkv GEMM. Tile 256x192 -> grid 256 blocks = 1/CU.
// Minimal 2-phase pipeline: all ds_reads of the current buffer first, then
// next tile's 7 global_load_lds into buf^1, then 48 MFMAs, one __syncthreads
// per K-tile. 8 waves (2M x 4N), wave tile 128x48. Each N-tile (192 cols)
// = one head group -> uniform epilogue. LDS 112 KB. (round-2, unchanged)
// ---------------------------------------------------------------------------
__global__ __launch_bounds__(512, 2) void gemm_qkv_kernel(
    const bf16* __restrict__ xnt, const bf16* __restrict__ Wb,
    const float* __restrict__ bs, bf16* __restrict__ qkT, bf16* __restrict__ vv)
{
  const int bid = blockIdx.x;
  const int swz = (bid & 7) * 32 + (bid >> 3);   // bijective: 256 = 8 * 32
  const int bxn = swz >> 4, bym = swz & 15;      // per XCD: 2 N-panels x 16 M
  const int n0 = bxn * 192, m0 = bym * 256;
  const int head = bxn;

  __shared__ __align__(16) bf16 Al[2][256 * 64];
  __shared__ __align__(16) bf16 Bl[2][192 * 64];

  const int tid  = threadIdx.x;
  const int wave = tid >> 6, lane = tid & 63;
  const int quad = lane >> 4, l15 = lane & 15;
  const int wr = wave >> 2, wc = wave & 3;
  const int lrow = lane >> 3, lp = lane & 7;
  const int sc8 = (lp ^ lrow) << 3;   // pre-swizzled source chunk (elements)

  #define STAGE(bufn, kt) do {                                                \
    _Pragma("unroll")                                                         \
    for (int c = 0; c < 4; ++c)                                               \
      GLOAD_LDS16(xnt + (size_t)(m0 + c * 64 + wave * 8 + lrow) * 1024 +      \
                      (size_t)(kt) * 64 + sc8,                                \
                  &Al[bufn][(c * 64 + wave * 8) * 64]);                       \
    _Pragma("unroll")                                                         \
    for (int c = 0; c < 3; ++c)                                               \
      GLOAD_LDS16(Wb + (size_t)(n0 + c * 64 + wave * 8 + lrow) * 1024 +       \
                      (size_t)(kt) * 64 + sc8,                                \
                  &Bl[bufn][(c * 64 + wave * 8) * 64]);                       \
  } while (0)

  F4 acc[8][3];
  #pragma unroll
  for (int i = 0; i < 8; ++i)
    #pragma unroll
    for (int j = 0; j < 3; ++j) acc[i][j].v = (f32x4){0.f, 0.f, 0.f, 0.f};

  STAGE(0, 0);
  __syncthreads();

  for (int t = 0; t < 16; ++t) {
    const int cb = t & 1;

    bf16x8 af[2][8], bfr[2][3];
    #pragma unroll
    for (int kk = 0; kk < 2; ++kk) {
      #pragma unroll
      for (int nt = 0; nt < 3; ++nt)
        bfr[kk][nt] = SWZ(Bl[cb], wc * 48 + nt * 16 + l15, kk * 4 + quad);
      #pragma unroll
      for (int mt = 0; mt < 8; ++mt)
        af[kk][mt] = SWZ(Al[cb], wr * 128 + mt * 16 + l15, kk * 4 + quad);
    }

    if (t + 1 < 16) STAGE(cb ^ 1, t + 1);

    #pragma unroll
    for (int kk = 0; kk < 2; ++kk)
      #pragma unroll
      for (int mt = 0; mt < 8; ++mt)
        #pragma unroll
        for (int nt = 0; nt < 3; ++nt)
          acc[mt][nt].v = __builtin_amdgcn_mfma_f32_16x16x32_bf16(
              af[kk][mt], bfr[kk][nt], acc[mt][nt].v, 0, 0, 0);

    __syncthreads();
  }
  #undef STAGE

  const int z  = m0 >> 10;
  const int tb = (m0 & 1023) + wr * 128;
  #pragma unroll
  for (int nt = 0; nt < 3; ++nt) {
    const int r192 = wc * 48 + nt * 16;     // 0..176, wave-uniform
    const float bb = bs[n0 + r192 + l15];
    if (r192 < 128) {
      const int col = head * 128 + r192 + l15;
      #pragma unroll
      for (int mt = 0; mt < 8; ++mt)
        #pragma unroll
        for (int r = 0; r < 4; ++r) {
          const int m = m0 + wr * 128 + mt * 16 + quad * 4 + r;
          qkT[(size_t)m * 2048 + col] = (bf16)(acc[mt][nt].e[r] + bb);
        }
    } else {
      bf16* vrow = vv + ((size_t)z * 1024 + head * 64 + (r192 - 128) + l15) * 1024;
      #pragma unroll
      for (int mt = 0; mt < 8; ++mt) {
        B4 pk;
        #pragma unroll
        for (int r = 0; r < 4; ++r) pk.e[r] = (bf16)(acc[mt][nt].e[r] + bb);
        *(bf16x4*)&vrow[tb + mt * 16 + quad * 4] = pk.v;
      }
    }
  }
}

// ---------------------------------------------------------------------------
// Kernel 4: proj GEMM v3. One GEMM M=1024(ch) x N=4096(b*t) x K=1024, tile
// 128x128, grid 256 = 1/CU. Fix for v2's regression: BK=128 (two 64-wide
// sub-tiles, same SWZ machinery) -> 32 MFMA/wave per barrier-pair (v2 had
// 16, too few to cover staging latency at 1 block/CU). 8 K-steps; per step
// 8 DMA calls + 24 ds_reads + 32 MFMA + one barrier. LDS 128 KB.
// K order (h,kk ascending) identical to two successive 64-steps -> same
// numerics as v1/v2. out = acc + bias + residual (fp32).
// ---------------------------------------------------------------------------
__global__ __launch_bounds__(512, 2) void gemm_proj_kernel(
    const bf16* __restrict__ Pb, const bf16* __restrict__ Bt,
    float* __restrict__ out, const float* __restrict__ bias,
    const float* __restrict__ resf)
{
  const int bid = blockIdx.x;
  const int swz = (bid & 7) * 32 + (bid >> 3);   // bijective: 256 = 8 * 32
  const int mp = swz & 7, np = swz >> 3;
  const int m0 = mp * 128;                       // channel base
  const int n0g = np * 128;                      // global t base (b*1024+t)

  __shared__ __align__(16) bf16 Al[2][2][128 * 64]; // [buf][k-half][row][64]
  __shared__ __align__(16) bf16 Bl[2][2][128 * 64];

  const int tid  = threadIdx.x;
  const int wave = tid >> 6, lane = tid & 63;
  const int quad = lane >> 4, l15 = lane & 15;
  const int wr = wave >> 2, wc = wave & 3;       // 2(m) x 4(n)
  const int lrow = lane >> 3, lp = lane & 7;
  const int sc8 = (lp ^ lrow) << 3;

  #define STAGE(bufn, kt) do {                                                \
    _Pragma("unroll")                                                         \
    for (int h = 0; h < 2; ++h) {                                             \
      _Pragma("unroll")                                                       \
      for (int c = 0; c < 2; ++c) {                                           \
        GLOAD_LDS16(Pb + (size_t)(m0 + c * 64 + wave * 8 + lrow) * 1024 +     \
                        (size_t)(kt) * 128 + h * 64 + sc8,                    \
                    &Al[bufn][h][(c * 64 + wave * 8) * 64]);                  \
        GLOAD_LDS16(Bt + (size_t)(n0g + c * 64 + wave * 8 + lrow) * 1024 +    \
                        (size_t)(kt) * 128 + h * 64 + sc8,                    \
                    &Bl[bufn][h][(c * 64 + wave * 8) * 64]);                  \
      }                                                                       \
    }                                                                         \
  } while (0)

  F4 acc[4][2];
  #pragma unroll
  for (int i = 0; i < 4; ++i)
    #pragma unroll
    for (int j = 0; j < 2; ++j) acc[i][j].v = (f32x4){0.f, 0.f, 0.f, 0.f};

  STAGE(0, 0);
  __syncthreads();

  for (int t = 0; t < 8; ++t) {
    const int cb = t & 1;

    bf16x8 af[2][2][4], bfr[2][2][2];
    #pragma unroll
    for (int h = 0; h < 2; ++h)
      #pragma unroll
      for (int kk = 0; kk < 2; ++kk) {
        #pragma unroll
        for (int mt = 0; mt < 4; ++mt)
          af[h][kk][mt] = SWZ(Al[cb][h], wr * 64 + mt * 16 + l15, kk * 4 + quad);
        #pragma unroll
        for (int nt = 0; nt < 2; ++nt)
          bfr[h][kk][nt] = SWZ(Bl[cb][h], wc * 32 + nt * 16 + l15, kk * 4 + quad);
      }

    if (t + 1 < 8) STAGE(cb ^ 1, t + 1);

    #pragma unroll
    for (int h = 0; h < 2; ++h)
      #pragma unroll
      for (int kk = 0; kk < 2; ++kk)
        #pragma unroll
        for (int mt = 0; mt < 4; ++mt)
          #pragma unroll
          for (int nt = 0; nt < 2; ++nt)
            acc[mt][nt].v = __builtin_amdgcn_mfma_f32_16x16x32_bf16(
                af[h][kk][mt], bfr[h][kk][nt], acc[mt][nt].v, 0, 0, 0);

    __syncthreads();
  }
  #undef STAGE

  const int z  = n0g >> 10;                 // block-uniform (128 | 1024)
  const int nl = n0g & 1023;
  const size_t zoff = (size_t)z * 1024 * 1024;
  #pragma unroll
  for (int mt = 0; mt < 4; ++mt) {
    #pragma unroll
    for (int r = 0; r < 4; ++r) {
      const int m = m0 + wr * 64 + mt * 16 + quad * 4 + r;
      const float bb = bias[m];
      #pragma unroll
      for (int nt = 0; nt < 2; ++nt) {
        const int n = nl + wc * 32 + nt * 16 + l15;
        out[zoff + (size_t)m * 1024 + n] =
            acc[mt][nt].e[r] + bb + resf[zoff + (size_t)m * 1024 + n];
      }
    }
  }
}

// ---------------------------------------------------------------------------
// Kernel 3: attention, S^T + no-max softmax, 128-t blocks: each wave owns
// TWO independent 16-t bands. Round-4 change: prefetch DMA moved AFTER the
// band-invariant ak/bv ds_reads (verified ds-reads-first recipe) so no
// current-buffer fragment read follows a same-chunk DMA in program order.
// grid (16,8,4) = 512 blocks. LDS: qP 16K + kl 2x8K + vl 2x8K = 48 KB.
// ---------------------------------------------------------------------------
__global__ __launch_bounds__(256) void attn_kernel(
    const bf16* __restrict__ qkTin, const bf16* __restrict__ vmat,
    bf16* __restrict__ aout)
{
  const int h = blockIdx.x, tt = blockIdx.y, z = blockIdx.z;
  const bf16* qk = qkTin + (size_t)z * 1024 * 2048;
  const bf16* vp = vmat + (size_t)z * 1024 * 1024 + (size_t)(h * 64) * 1024;
  aout += (size_t)z * 1024 * 1024;
  const int t0 = tt * 128;

  __shared__ __align__(16) bf16 qP[128 * 64];     // q rows (init) then P bands
  __shared__ __align__(16) bf16 kl[2][64 * 64];
  __shared__ __align__(16) bf16 vl[2][64 * 64];

  const int tid  = threadIdx.x;
  const int wave = tid >> 6, lane = tid & 63;
  const int quad = lane >> 4, l15 = lane & 15;
  const int lrow = lane >> 3, lp = lane & 7;

  #pragma unroll
  for (int c = 0; c < 4; ++c) {
    const int row = wave * 32 + c * 8 + lrow;
    const int c8  = lp ^ (row & 7);
    GLOAD_LDS16(qk + (size_t)(t0 + row) * 2048 + h * 128 + c8 * 8,
                &qP[(wave * 32 + c * 8) * 64]);
  }
  const int r0 = wave * 16 + lrow, r1 = wave * 16 + 8 + lrow;
  const int c80 = lp ^ (r0 & 7), c81 = lp ^ (r1 & 7);
  GLOAD_LDS16(qk + (size_t)r0 * 2048 + h * 128 + 64 + c80 * 8, &kl[0][(wave * 16) * 64]);
  GLOAD_LDS16(qk + (size_t)r1 * 2048 + h * 128 + 64 + c81 * 8, &kl[0][(wave * 16 + 8) * 64]);
  GLOAD_LDS16(vp + (size_t)r0 * 1024 + c80 * 8, &vl[0][(wave * 16) * 64]);
  GLOAD_LDS16(vp + (size_t)r1 * 1024 + c81 * 8, &vl[0][(wave * 16 + 8) * 64]);
  __syncthreads();

  bf16x8 bq0[2], bq1[2];
  int prow[2];
  #pragma unroll
  for (int b = 0; b < 2; ++b) {
    const int Rq = wave * 32 + b * 16 + l15;
    bq0[b] = SWZ(qP, Rq, quad);
    bq1[b] = SWZ(qP, Rq, quad + 4);
    prow[b] = Rq;
  }

  float l_i[2] = {0.f, 0.f};
  F4 oacc[2][4];
  #pragma unroll
  for (int b = 0; b < 2; ++b)
    #pragma unroll
    for (int ct = 0; ct < 4; ++ct) oacc[b][ct].v = (f32x4){0.f, 0.f, 0.f, 0.f};

  const int pq8 = (quad & 1) * 4;

  int buf = 0;
  for (int s0 = 0; s0 < 1024; s0 += 64) {
    // 1) Band-invariant k and v fragments: read FIRST (no ds_read after a
    //    same-chunk DMA in program order).
    bf16x8 ak0[4], ak1[4], bv[2][4];
    #pragma unroll
    for (int st = 0; st < 4; ++st) {
      const int Rk = st * 16 + l15;
      ak0[st] = SWZ(kl[buf], Rk, quad);
      ak1[st] = SWZ(kl[buf], Rk, quad + 4);
    }
    #pragma unroll
    for (int ks = 0; ks < 2; ++ks)
      #pragma unroll
      for (int ct = 0; ct < 4; ++ct)
        bv[ks][ct] = SWZ(vl[buf], ct * 16 + l15, ks * 4 + quad);

    // 2) Prefetch next chunk.
    if (s0 + 64 < 1024) {
      const int nb = buf ^ 1, sn = s0 + 64;
      GLOAD_LDS16(qk + (size_t)(sn + r0) * 2048 + h * 128 + 64 + c80 * 8,
                  &kl[nb][(wave * 16) * 64]);
      GLOAD_LDS16(qk + (size_t)(sn + r1) * 2048 + h * 128 + 64 + c81 * 8,
                  &kl[nb][(wave * 16 + 8) * 64]);
      GLOAD_LDS16(vp + (size_t)r0 * 1024 + sn + c80 * 8, &vl[nb][(wave * 16) * 64]);
      GLOAD_LDS16(vp + (size_t)r1 * 1024 + sn + c81 * 8, &vl[nb][(wave * 16 + 8) * 64]);
    }

    // 3) Two bands: QK^T -> exp -> P (LDS round-trip) -> PV.
    #pragma unroll
    for (int b = 0; b < 2; ++b) {
      F4 sacc[4];
      #pragma unroll
      for (int st = 0; st < 4; ++st) sacc[st].v = (f32x4){0.f, 0.f, 0.f, 0.f};
      #pragma unroll
      for (int st = 0; st < 4; ++st) {
        sacc[st].v = __builtin_amdgcn_mfma_f32_16x16x32_bf16(ak0[st], bq0[b], sacc[st].v, 0, 0, 0);
        sacc[st].v = __builtin_amdgcn_mfma_f32_16x16x32_bf16(ak1[st], bq1[b], sacc[st].v, 0, 0, 0);
      }

      bf16* const pbase = &qP[(size_t)prow[b] * 64];
      #pragma unroll
      for (int st = 0; st < 4; ++st) {
        B4 pk;
        #pragma unroll
        for (int r = 0; r < 4; ++r) {
          const float p = __builtin_amdgcn_exp2f(sacc[st].e[r]);
          l_i[b] += p;
          pk.e[r] = (bf16)p;
        }
        const int c8 = (st * 2 + (quad >> 1)) ^ (prow[b] & 7);
        *(bf16x4*)(pbase + (c8 << 3) + pq8) = pk.v;
      }

      #pragma unroll
      for (int ks = 0; ks < 2; ++ks) {
        const bf16x8 ap = SWZ(qP, prow[b], ks * 4 + quad);
        #pragma unroll
        for (int ct = 0; ct < 4; ++ct)
          oacc[b][ct].v = __builtin_amdgcn_mfma_f32_16x16x32_bf16(
              ap, bv[ks][ct], oacc[b][ct].v, 0, 0, 0);
      }
    }
    __syncthreads();   // drains next-chunk DMA; all waves done with buf
    buf ^= 1;
  }

  #pragma unroll
  for (int b = 0; b < 2; ++b) {
    float li = l_i[b];
    li += __shfl_xor(li, 16);
    li += __shfl_xor(li, 32);
    const float inv = 1.f / li;
    float iv[4];
    #pragma unroll
    for (int r = 0; r < 4; ++r) iv[r] = __shfl(inv, quad * 4 + r);
    #pragma unroll
    for (int r = 0; r < 4; ++r) {
      const int t = t0 + wave * 32 + b * 16 + quad * 4 + r;
      #pragma unroll
      for (int ct = 0; ct < 4; ++ct)
        aout[(size_t)t * 1024 + h * 64 + ct * 16 + l15] = (bf16)(oacc[b][ct].e[r] * iv[r]);
    }
  }
}

// ---------------------------------------------------------------------------
// ws layout:
//   xnt [b][t][c] : ws[ 0,  8 MB)
//   qkT [b][t][n] : ws[ 8, 24 MB)
//   v   [b][ov][t]: ws[24, 32 MB)
//   a^T [b][t][c] : ws[32, 40 MB)
//   Wb / Pb / bs  : ws[40, 48 MB) + 12 KB
// ---------------------------------------------------------------------------
extern "C" void kernel_launch(void* const* d_in, const int* in_sizes, int n_in,
                              void* d_out, int out_size, void* d_ws, size_t ws_size,
                              hipStream_t stream)
{
  const float* x    = (const float*)d_in[0];
  const float* nw   = (const float*)d_in[1];
  const float* nb   = (const float*)d_in[2];
  const float* qkvw = (const float*)d_in[3];
  const float* qkvb = (const float*)d_in[4];
  const float* pw   = (const float*)d_in[5];
  const float* pb   = (const float*)d_in[6];
  float* out = (float*)d_out;

  const long M1 = 1024L * 1024L;
  bf16*  xnt = (bf16*)d_ws;
  bf16*  qkT = xnt + 4 * M1;
  bf16*  vv  = xnt + 12 * M1;
  bf16*  at  = xnt + 16 * M1;
  bf16*  Wb  = xnt + 20 * M1;
  bf16*  Pb  = xnt + 23 * M1;
  float* bs  = (float*)(xnt + 24 * M1);

  conv_w_kernel<<<dim3(4096), dim3(256), 0, stream>>>(qkvw, qkvb, pw, Wb, Pb, bs);
  gn_t_kernel<<<dim3(128), dim3(256), 0, stream>>>(x, nw, nb, xnt);
  gemm_qkv_kernel<<<dim3(256), dim3(512), 0, stream>>>(xnt, Wb, bs, qkT, vv);
  attn_kernel<<<dim3(16, 8, 4), dim3(256), 0, stream>>>(qkT, vv, at);
  gemm_proj_kernel<<<dim3(256), dim3(512), 0, stream>>>(Pb, at, out, pb, x);
}

// Round 5
// 174.025 us; speedup vs baseline: 1.0397x; 1.0114x over previous
//
#include <hip/hip_runtime.h>
#include <hip/hip_bf16.h>

typedef __bf16 bf16;
typedef bf16  bf16x4 __attribute__((ext_vector_type(4)));
typedef bf16  bf16x8 __attribute__((ext_vector_type(8)));
typedef float f32x4  __attribute__((ext_vector_type(4)));

union B8 { bf16x8 v; bf16 e[8]; };
union B4 { bf16x4 v; bf16 e[4]; };
union F4 { f32x4 v; float e[4]; };

// Async global->LDS DMA, 16 B per lane (wave-uniform LDS base, lane i ->
// base + i*16).
#define GLOAD_LDS16(g, l)                                            \
  __builtin_amdgcn_global_load_lds(                                  \
      (const __attribute__((address_space(1))) void*)(g),            \
      (__attribute__((address_space(3))) void*)(l), 16, 0, 0)

// Swizzled tile: row stride 64 bf16, 16B chunk p = c8 ^ (row & 7).
#define SWZ(arr, R, c8) (*(const bf16x8*)&(arr)[(size_t)(R) * 64 + (((c8) ^ ((R) & 7)) << 3)])

// ---------------------------------------------------------------------------
// Kernel 0: weight conversion fp32 -> bf16. q/k rows scaled by
// 0.35355339 * sqrt(log2(e)) = 0.42468158 -> scores arrive in log2 domain.
// ---------------------------------------------------------------------------
__global__ __launch_bounds__(256) void conv_w_kernel(
    const float* __restrict__ qkvw, const float* __restrict__ qkvb,
    const float* __restrict__ pw,
    bf16* __restrict__ Wb, bf16* __restrict__ Pb, float* __restrict__ bs)
{
  const int row = blockIdx.x;
  const int tid = threadIdx.x;
  if (row < 3072) {
    const float s = ((row % 192) < 128) ? 0.42468158f : 1.0f;
    const float4 a = ((const float4*)(qkvw + (size_t)row * 1024))[tid];
    B4 o;
    o.e[0] = (bf16)(a.x * s); o.e[1] = (bf16)(a.y * s);
    o.e[2] = (bf16)(a.z * s); o.e[3] = (bf16)(a.w * s);
    ((bf16x4*)(Wb + (size_t)row * 1024))[tid] = o.v;
    if (tid == 0) bs[row] = qkvb[row] * s;
  } else {
    const int r = row - 3072;
    const float4 a = ((const float4*)(pw + (size_t)r * 1024))[tid];
    B4 o;
    o.e[0] = (bf16)a.x; o.e[1] = (bf16)a.y;
    o.e[2] = (bf16)a.z; o.e[3] = (bf16)a.w;
    ((bf16x4*)(Pb + (size_t)r * 1024))[tid] = o.v;
  }
}

// ---------------------------------------------------------------------------
// Kernel 1: GroupNorm, transposed output: x[b][c][t] fp32 -> xnt[b][t][c] bf16.
// ---------------------------------------------------------------------------
__global__ __launch_bounds__(256) void gn_t_kernel(
    const float* __restrict__ x, const float* __restrict__ w,
    const float* __restrict__ bias, bf16* __restrict__ xnt)
{
  const int blk = blockIdx.x;
  const int b = blk >> 5, g = blk & 31;
  const float* xp = x + (size_t)(b * 1024 + g * 32) * 1024;
  const int tid = threadIdx.x;

  float s = 0.f, ss = 0.f;
  for (int ch = tid; ch < 4096; ch += 256) {
    const float4* p = (const float4*)(xp + (size_t)ch * 8);
    float4 u0 = p[0], u1 = p[1];
    s  += u0.x + u0.y + u0.z + u0.w + u1.x + u1.y + u1.z + u1.w;
    ss += u0.x*u0.x + u0.y*u0.y + u0.z*u0.z + u0.w*u0.w
        + u1.x*u1.x + u1.y*u1.y + u1.z*u1.z + u1.w*u1.w;
  }
  #pragma unroll
  for (int m = 1; m < 64; m <<= 1) { s += __shfl_xor(s, m); ss += __shfl_xor(ss, m); }

  __shared__ float red[8];
  __shared__ float stats[2];
  const int wave = tid >> 6, lane = tid & 63;
  if (lane == 0) { red[wave] = s; red[4 + wave] = ss; }
  __syncthreads();
  if (tid == 0) {
    float ts  = red[0] + red[1] + red[2] + red[3];
    float tss = red[4] + red[5] + red[6] + red[7];
    float mu  = ts * (1.f / 32768.f);
    float var = tss * (1.f / 32768.f) - mu * mu;
    stats[0] = mu;
    stats[1] = rsqrtf(var + 1e-5f);
  }
  __syncthreads();
  const float mu = stats[0], rs = stats[1];

  for (int ti = 0; ti < 4; ++ti) {
    const int t = ti * 256 + tid;
    B8 o[4];
    #pragma unroll
    for (int cc = 0; cc < 32; ++cc) {
      const float wt = w[g * 32 + cc] * rs;
      const float bsv = bias[g * 32 + cc];
      const float v = xp[(size_t)cc * 1024 + t];
      o[cc >> 3].e[cc & 7] = (bf16)((v - mu) * wt + bsv);
    }
    bf16* dst = xnt + (size_t)(b * 1024 + t) * 1024 + g * 32;
    #pragma unroll
    for (int j = 0; j < 4; ++j) *(bf16x8*)(dst + j * 8) = o[j].v;
  }
}

// ---------------------------------------------------------------------------
// Kernel 2: merged qkv GEMM. Tile 256x192 -> grid 256 blocks = 1/CU.
// Minimal 2-phase pipeline: all ds_reads of the current buffer first, then
// next tile's 7 global_load_lds into buf^1, then 48 MFMAs, one __syncthreads
// per K-tile. 8 waves (2M x 4N), wave tile 128x48. Each N-tile (192 cols)
// = one head group -> uniform epilogue. LDS 112 KB.
// Round-5: qkT epilogue stores nt-innermost -> per (m,r) the wave's three
// 32B chunks form one 96B contiguous burst (was isolated 32B partial-line
// stores, ~1.6x write amplification).
// ---------------------------------------------------------------------------
__global__ __launch_bounds__(512, 2) void gemm_qkv_kernel(
    const bf16* __restrict__ xnt, const bf16* __restrict__ Wb,
    const float* __restrict__ bs, bf16* __restrict__ qkT, bf16* __restrict__ vv)
{
  const int bid = blockIdx.x;
  const int swz = (bid & 7) * 32 + (bid >> 3);   // bijective: 256 = 8 * 32
  const int bxn = swz >> 4, bym = swz & 15;      // per XCD: 2 N-panels x 16 M
  const int n0 = bxn * 192, m0 = bym * 256;
  const int head = bxn;

  __shared__ __align__(16) bf16 Al[2][256 * 64];
  __shared__ __align__(16) bf16 Bl[2][192 * 64];

  const int tid  = threadIdx.x;
  const int wave = tid >> 6, lane = tid & 63;
  const int quad = lane >> 4, l15 = lane & 15;
  const int wr = wave >> 2, wc = wave & 3;
  const int lrow = lane >> 3, lp = lane & 7;
  const int sc8 = (lp ^ lrow) << 3;   // pre-swizzled source chunk (elements)

  #define STAGE(bufn, kt) do {                                                \
    _Pragma("unroll")                                                         \
    for (int c = 0; c < 4; ++c)                                               \
      GLOAD_LDS16(xnt + (size_t)(m0 + c * 64 + wave * 8 + lrow) * 1024 +      \
                      (size_t)(kt) * 64 + sc8,                                \
                  &Al[bufn][(c * 64 + wave * 8) * 64]);                       \
    _Pragma("unroll")                                                         \
    for (int c = 0; c < 3; ++c)                                               \
      GLOAD_LDS16(Wb + (size_t)(n0 + c * 64 + wave * 8 + lrow) * 1024 +       \
                      (size_t)(kt) * 64 + sc8,                                \
                  &Bl[bufn][(c * 64 + wave * 8) * 64]);                       \
  } while (0)

  F4 acc[8][3];
  #pragma unroll
  for (int i = 0; i < 8; ++i)
    #pragma unroll
    for (int j = 0; j < 3; ++j) acc[i][j].v = (f32x4){0.f, 0.f, 0.f, 0.f};

  STAGE(0, 0);
  __syncthreads();

  for (int t = 0; t < 16; ++t) {
    const int cb = t & 1;

    bf16x8 af[2][8], bfr[2][3];
    #pragma unroll
    for (int kk = 0; kk < 2; ++kk) {
      #pragma unroll
      for (int nt = 0; nt < 3; ++nt)
        bfr[kk][nt] = SWZ(Bl[cb], wc * 48 + nt * 16 + l15, kk * 4 + quad);
      #pragma unroll
      for (int mt = 0; mt < 8; ++mt)
        af[kk][mt] = SWZ(Al[cb], wr * 128 + mt * 16 + l15, kk * 4 + quad);
    }

    if (t + 1 < 16) STAGE(cb ^ 1, t + 1);

    #pragma unroll
    for (int kk = 0; kk < 2; ++kk)
      #pragma unroll
      for (int mt = 0; mt < 8; ++mt)
        #pragma unroll
        for (int nt = 0; nt < 3; ++nt)
          acc[mt][nt].v = __builtin_amdgcn_mfma_f32_16x16x32_bf16(
              af[kk][mt], bfr[kk][nt], acc[mt][nt].v, 0, 0, 0);

    __syncthreads();
  }
  #undef STAGE

  const int z  = m0 >> 10;
  const int tb = (m0 & 1023) + wr * 128;
  float bbv[3];
  #pragma unroll
  for (int nt = 0; nt < 3; ++nt) bbv[nt] = bs[n0 + wc * 48 + nt * 16 + l15];

  // q/k columns: nt innermost so the 3 chunks of one row merge (96B burst).
  #pragma unroll
  for (int mt = 0; mt < 8; ++mt)
    #pragma unroll
    for (int r = 0; r < 4; ++r) {
      const int m = m0 + wr * 128 + mt * 16 + quad * 4 + r;
      #pragma unroll
      for (int nt = 0; nt < 3; ++nt) {
        const int r192 = wc * 48 + nt * 16;   // wave-uniform
        if (r192 < 128)
          qkT[(size_t)m * 2048 + head * 128 + r192 + l15] =
              (bf16)(acc[mt][nt].e[r] + bbv[nt]);
      }
    }
  // v rows: original packed form (4 consecutive t per 8B store).
  #pragma unroll
  for (int nt = 0; nt < 3; ++nt) {
    const int r192 = wc * 48 + nt * 16;
    if (r192 >= 128) {
      bf16* vrow = vv + ((size_t)z * 1024 + head * 64 + (r192 - 128) + l15) * 1024;
      #pragma unroll
      for (int mt = 0; mt < 8; ++mt) {
        B4 pk;
        #pragma unroll
        for (int r = 0; r < 4; ++r) pk.e[r] = (bf16)(acc[mt][nt].e[r] + bbv[nt]);
        *(bf16x4*)&vrow[tb + mt * 16 + quad * 4] = pk.v;
      }
    }
  }
}

// ---------------------------------------------------------------------------
// Kernel 4: proj GEMM v3. One GEMM M=1024(ch) x N=4096(b*t) x K=1024, tile
// 128x128, grid 256 = 1/CU, BK=128 (two 64-wide sub-tiles) -> 32 MFMA/wave
// per barrier-pair. LDS 128 KB. out = acc + bias + residual (fp32).
// ---------------------------------------------------------------------------
__global__ __launch_bounds__(512, 2) void gemm_proj_kernel(
    const bf16* __restrict__ Pb, const bf16* __restrict__ Bt,
    float* __restrict__ out, const float* __restrict__ bias,
    const float* __restrict__ resf)
{
  const int bid = blockIdx.x;
  const int swz = (bid & 7) * 32 + (bid >> 3);   // bijective: 256 = 8 * 32
  const int mp = swz & 7, np = swz >> 3;
  const int m0 = mp * 128;                       // channel base
  const int n0g = np * 128;                      // global t base (b*1024+t)

  __shared__ __align__(16) bf16 Al[2][2][128 * 64]; // [buf][k-half][row][64]
  __shared__ __align__(16) bf16 Bl[2][2][128 * 64];

  const int tid  = threadIdx.x;
  const int wave = tid >> 6, lane = tid & 63;
  const int quad = lane >> 4, l15 = lane & 15;
  const int wr = wave >> 2, wc = wave & 3;       // 2(m) x 4(n)
  const int lrow = lane >> 3, lp = lane & 7;
  const int sc8 = (lp ^ lrow) << 3;

  #define STAGE(bufn, kt) do {                                                \
    _Pragma("unroll")                                                         \
    for (int h = 0; h < 2; ++h) {                                             \
      _Pragma("unroll")                                                       \
      for (int c = 0; c < 2; ++c) {                                           \
        GLOAD_LDS16(Pb + (size_t)(m0 + c * 64 + wave * 8 + lrow) * 1024 +     \
                        (size_t)(kt) * 128 + h * 64 + sc8,                    \
                    &Al[bufn][h][(c * 64 + wave * 8) * 64]);                  \
        GLOAD_LDS16(Bt + (size_t)(n0g + c * 64 + wave * 8 + lrow) * 1024 +    \
                        (size_t)(kt) * 128 + h * 64 + sc8,                    \
                    &Bl[bufn][h][(c * 64 + wave * 8) * 64]);                  \
      }                                                                       \
    }                                                                         \
  } while (0)

  F4 acc[4][2];
  #pragma unroll
  for (int i = 0; i < 4; ++i)
    #pragma unroll
    for (int j = 0; j < 2; ++j) acc[i][j].v = (f32x4){0.f, 0.f, 0.f, 0.f};

  STAGE(0, 0);
  __syncthreads();

  for (int t = 0; t < 8; ++t) {
    const int cb = t & 1;

    bf16x8 af[2][2][4], bfr[2][2][2];
    #pragma unroll
    for (int h = 0; h < 2; ++h)
      #pragma unroll
      for (int kk = 0; kk < 2; ++kk) {
        #pragma unroll
        for (int mt = 0; mt < 4; ++mt)
          af[h][kk][mt] = SWZ(Al[cb][h], wr * 64 + mt * 16 + l15, kk * 4 + quad);
        #pragma unroll
        for (int nt = 0; nt < 2; ++nt)
          bfr[h][kk][nt] = SWZ(Bl[cb][h], wc * 32 + nt * 16 + l15, kk * 4 + quad);
      }

    if (t + 1 < 8) STAGE(cb ^ 1, t + 1);

    #pragma unroll
    for (int h = 0; h < 2; ++h)
      #pragma unroll
      for (int kk = 0; kk < 2; ++kk)
        #pragma unroll
        for (int mt = 0; mt < 4; ++mt)
          #pragma unroll
          for (int nt = 0; nt < 2; ++nt)
            acc[mt][nt].v = __builtin_amdgcn_mfma_f32_16x16x32_bf16(
                af[h][kk][mt], bfr[h][kk][nt], acc[mt][nt].v, 0, 0, 0);

    __syncthreads();
  }
  #undef STAGE

  const int z  = n0g >> 10;                 // block-uniform (128 | 1024)
  const int nl = n0g & 1023;
  const size_t zoff = (size_t)z * 1024 * 1024;
  #pragma unroll
  for (int mt = 0; mt < 4; ++mt) {
    #pragma unroll
    for (int r = 0; r < 4; ++r) {
      const int m = m0 + wr * 64 + mt * 16 + quad * 4 + r;
      const float bb = bias[m];
      #pragma unroll
      for (int nt = 0; nt < 2; ++nt) {
        const int n = nl + wc * 32 + nt * 16 + l15;
        out[zoff + (size_t)m * 1024 + n] =
            acc[mt][nt].e[r] + bb + resf[zoff + (size_t)m * 1024 + n];
      }
    }
  }
}

// ---------------------------------------------------------------------------
// Kernel 3: attention v2. QBLK 256 (was 128): 8 waves, grid (16,4,4) = 256
// blocks = 1/CU. Per-wave structure IDENTICAL to the verified 128-t version
// (each wave owns 2 independent 16-t bands at rows wave*32 + b*16); only the
// k/v staging split changes (8 rows/wave, 1 DMA call per matrix per chunk).
// K/V staging bytes and barriers per unit work HALVE. tt-blocks sharing
// (h,z) land on the same XCD (grid.x=16 -> XCD = h%8) -> k/v L2-warm.
// LDS: qP 32K (q then P bands) + kl 2x8K + vl 2x8K = 64 KB.
// ---------------------------------------------------------------------------
__global__ __launch_bounds__(512) void attn_kernel(
    const bf16* __restrict__ qkTin, const bf16* __restrict__ vmat,
    bf16* __restrict__ aout)
{
  const int h = blockIdx.x, tt = blockIdx.y, z = blockIdx.z;
  const bf16* qk = qkTin + (size_t)z * 1024 * 2048;
  const bf16* vp = vmat + (size_t)z * 1024 * 1024 + (size_t)(h * 64) * 1024;
  aout += (size_t)z * 1024 * 1024;
  const int t0 = tt * 256;

  __shared__ __align__(16) bf16 qP[256 * 64];     // q rows (init) then P bands
  __shared__ __align__(16) bf16 kl[2][64 * 64];
  __shared__ __align__(16) bf16 vl[2][64 * 64];

  const int tid  = threadIdx.x;
  const int wave = tid >> 6, lane = tid & 63;     // wave 0..7
  const int quad = lane >> 4, l15 = lane & 15;
  const int lrow = lane >> 3, lp = lane & 7;

  // Stage q: wave stages rows [wave*32, +32): 4 DMA calls
  #pragma unroll
  for (int c = 0; c < 4; ++c) {
    const int row = wave * 32 + c * 8 + lrow;
    const int c8  = lp ^ (row & 7);
    GLOAD_LDS16(qk + (size_t)(t0 + row) * 2048 + h * 128 + c8 * 8,
                &qP[(wave * 32 + c * 8) * 64]);
  }
  // First k/v chunk: wave stages 8 rows each (1 call per matrix)
  const int r0 = wave * 8 + lrow;                 // 0..63
  const int c80 = lp ^ (r0 & 7);                  // = lp ^ lrow
  GLOAD_LDS16(qk + (size_t)r0 * 2048 + h * 128 + 64 + c80 * 8, &kl[0][(wave * 8) * 64]);
  GLOAD_LDS16(vp + (size_t)r0 * 1024 + c80 * 8, &vl[0][(wave * 8) * 64]);
  __syncthreads();

  // Hoist q fragments for both bands; qP rows then reused as P bands.
  bf16x8 bq0[2], bq1[2];
  int prow[2];
  #pragma unroll
  for (int b = 0; b < 2; ++b) {
    const int Rq = wave * 32 + b * 16 + l15;
    bq0[b] = SWZ(qP, Rq, quad);
    bq1[b] = SWZ(qP, Rq, quad + 4);
    prow[b] = Rq;
  }

  float l_i[2] = {0.f, 0.f};
  F4 oacc[2][4];
  #pragma unroll
  for (int b = 0; b < 2; ++b)
    #pragma unroll
    for (int ct = 0; ct < 4; ++ct) oacc[b][ct].v = (f32x4){0.f, 0.f, 0.f, 0.f};

  const int pq8 = (quad & 1) * 4;

  int buf = 0;
  for (int s0 = 0; s0 < 1024; s0 += 64) {
    // 1) Band-invariant k and v fragments: read FIRST (ds-reads-first recipe).
    bf16x8 ak0[4], ak1[4], bv[2][4];
    #pragma unroll
    for (int st = 0; st < 4; ++st) {
      const int Rk = st * 16 + l15;
      ak0[st] = SWZ(kl[buf], Rk, quad);
      ak1[st] = SWZ(kl[buf], Rk, quad + 4);
    }
    #pragma unroll
    for (int ks = 0; ks < 2; ++ks)
      #pragma unroll
      for (int ct = 0; ct < 4; ++ct)
        bv[ks][ct] = SWZ(vl[buf], ct * 16 + l15, ks * 4 + quad);

    // 2) Prefetch next chunk (2 DMA calls per wave).
    if (s0 + 64 < 1024) {
      const int nb = buf ^ 1, sn = s0 + 64;
      GLOAD_LDS16(qk + (size_t)(sn + r0) * 2048 + h * 128 + 64 + c80 * 8,
                  &kl[nb][(wave * 8) * 64]);
      GLOAD_LDS16(vp + (size_t)r0 * 1024 + sn + c80 * 8, &vl[nb][(wave * 8) * 64]);
    }

    // 3) Two bands: QK^T -> exp -> P (LDS round-trip) -> PV.
    #pragma unroll
    for (int b = 0; b < 2; ++b) {
      F4 sacc[4];
      #pragma unroll
      for (int st = 0; st < 4; ++st) sacc[st].v = (f32x4){0.f, 0.f, 0.f, 0.f};
      #pragma unroll
      for (int st = 0; st < 4; ++st) {
        sacc[st].v = __builtin_amdgcn_mfma_f32_16x16x32_bf16(ak0[st], bq0[b], sacc[st].v, 0, 0, 0);
        sacc[st].v = __builtin_amdgcn_mfma_f32_16x16x32_bf16(ak1[st], bq1[b], sacc[st].v, 0, 0, 0);
      }

      bf16* const pbase = &qP[(size_t)prow[b] * 64];
      #pragma unroll
      for (int st = 0; st < 4; ++st) {
        B4 pk;
        #pragma unroll
        for (int r = 0; r < 4; ++r) {
          const float p = __builtin_amdgcn_exp2f(sacc[st].e[r]);
          l_i[b] += p;
          pk.e[r] = (bf16)p;
        }
        const int c8 = (st * 2 + (quad >> 1)) ^ (prow[b] & 7);
        *(bf16x4*)(pbase + (c8 << 3) + pq8) = pk.v;
      }

      #pragma unroll
      for (int ks = 0; ks < 2; ++ks) {
        const bf16x8 ap = SWZ(qP, prow[b], ks * 4 + quad);
        #pragma unroll
        for (int ct = 0; ct < 4; ++ct)
          oacc[b][ct].v = __builtin_amdgcn_mfma_f32_16x16x32_bf16(
              ap, bv[ks][ct], oacc[b][ct].v, 0, 0, 0);
      }
    }
    __syncthreads();   // drains next-chunk DMA; all waves done with buf
    buf ^= 1;
  }

  #pragma unroll
  for (int b = 0; b < 2; ++b) {
    float li = l_i[b];
    li += __shfl_xor(li, 16);
    li += __shfl_xor(li, 32);
    const float inv = 1.f / li;
    float iv[4];
    #pragma unroll
    for (int r = 0; r < 4; ++r) iv[r] = __shfl(inv, quad * 4 + r);
    #pragma unroll
    for (int r = 0; r < 4; ++r) {
      const int t = t0 + wave * 32 + b * 16 + quad * 4 + r;
      #pragma unroll
      for (int ct = 0; ct < 4; ++ct)
        aout[(size_t)t * 1024 + h * 64 + ct * 16 + l15] = (bf16)(oacc[b][ct].e[r] * iv[r]);
    }
  }
}

// ---------------------------------------------------------------------------
// ws layout:
//   xnt [b][t][c] : ws[ 0,  8 MB)
//   qkT [b][t][n] : ws[ 8, 24 MB)
//   v   [b][ov][t]: ws[24, 32 MB)
//   a^T [b][t][c] : ws[32, 40 MB)
//   Wb / Pb / bs  : ws[40, 48 MB) + 12 KB
// ---------------------------------------------------------------------------
extern "C" void kernel_launch(void* const* d_in, const int* in_sizes, int n_in,
                              void* d_out, int out_size, void* d_ws, size_t ws_size,
                              hipStream_t stream)
{
  const float* x    = (const float*)d_in[0];
  const float* nw   = (const float*)d_in[1];
  const float* nb   = (const float*)d_in[2];
  const float* qkvw = (const float*)d_in[3];
  const float* qkvb = (const float*)d_in[4];
  const float* pw   = (const float*)d_in[5];
  const float* pb   = (const float*)d_in[6];
  float* out = (float*)d_out;

  const long M1 = 1024L * 1024L;
  bf16*  xnt = (bf16*)d_ws;
  bf16*  qkT = xnt + 4 * M1;
  bf16*  vv  = xnt + 12 * M1;
  bf16*  at  = xnt + 16 * M1;
  bf16*  Wb  = xnt + 20 * M1;
  bf16*  Pb  = xnt + 23 * M1;
  float* bs  = (float*)(xnt + 24 * M1);

  conv_w_kernel<<<dim3(4096), dim3(256), 0, stream>>>(qkvw, qkvb, pw, Wb, Pb, bs);
  gn_t_kernel<<<dim3(128), dim3(256), 0, stream>>>(x, nw, nb, xnt);
  gemm_qkv_kernel<<<dim3(256), dim3(512), 0, stream>>>(xnt, Wb, bs, qkT, vv);
  attn_kernel<<<dim3(16, 4, 4), dim3(512), 0, stream>>>(qkT, vv, at);
  gemm_proj_kernel<<<dim3(256), dim3(512), 0, stream>>>(Pb, at, out, pb, x);
}

// Round 6
// 166.841 us; speedup vs baseline: 1.0845x; 1.0431x over previous
//
#include <hip/hip_runtime.h>
#include <hip/hip_bf16.h>

typedef __bf16 bf16;
typedef bf16  bf16x4 __attribute__((ext_vector_type(4)));
typedef bf16  bf16x8 __attribute__((ext_vector_type(8)));
typedef float f32x4  __attribute__((ext_vector_type(4)));

union B8 { bf16x8 v; bf16 e[8]; };
union B4 { bf16x4 v; bf16 e[4]; };
union F4 { f32x4 v; float e[4]; };

// Async global->LDS DMA, 16 B per lane (wave-uniform LDS base, lane i ->
// base + i*16).
#define GLOAD_LDS16(g, l)                                            \
  __builtin_amdgcn_global_load_lds(                                  \
      (const __attribute__((address_space(1))) void*)(g),            \
      (__attribute__((address_space(3))) void*)(l), 16, 0, 0)

// Swizzled tile: row stride 64 bf16, 16B chunk p = c8 ^ (row & 7).
#define SWZ(arr, R, c8) (*(const bf16x8*)&(arr)[(size_t)(R) * 64 + (((c8) ^ ((R) & 7)) << 3)])

// ---------------------------------------------------------------------------
// Kernel 0+1 fused: gn blocks (bid < 128) + weight-conversion blocks
// (bid-128 in [0,4096)). The two are data-independent; fusing removes the
// serialization bubble (gn alone used only 128 CUs, conv alone underfills
// per-block). gn blocks are dispatched FIRST so they occupy 128 CUs for
// their full duration while conv blocks stream through the rest.
// Both code paths are bit-identical to the previous separate kernels.
// ---------------------------------------------------------------------------
__global__ __launch_bounds__(256) void pre_kernel(
    const float* __restrict__ x, const float* __restrict__ w,
    const float* __restrict__ bias, bf16* __restrict__ xnt,
    const float* __restrict__ qkvw, const float* __restrict__ qkvb,
    const float* __restrict__ pw,
    bf16* __restrict__ Wb, bf16* __restrict__ Pb, float* __restrict__ bs)
{
  const int tid = threadIdx.x;

  if (blockIdx.x >= 128) {
    // ---- weight conversion (was conv_w_kernel) ----
    const int row = blockIdx.x - 128;
    if (row < 3072) {
      const float s = ((row % 192) < 128) ? 0.42468158f : 1.0f;
      const float4 a = ((const float4*)(qkvw + (size_t)row * 1024))[tid];
      B4 o;
      o.e[0] = (bf16)(a.x * s); o.e[1] = (bf16)(a.y * s);
      o.e[2] = (bf16)(a.z * s); o.e[3] = (bf16)(a.w * s);
      ((bf16x4*)(Wb + (size_t)row * 1024))[tid] = o.v;
      if (tid == 0) bs[row] = qkvb[row] * s;
    } else {
      const int r = row - 3072;
      const float4 a = ((const float4*)(pw + (size_t)r * 1024))[tid];
      B4 o;
      o.e[0] = (bf16)a.x; o.e[1] = (bf16)a.y;
      o.e[2] = (bf16)a.z; o.e[3] = (bf16)a.w;
      ((bf16x4*)(Pb + (size_t)r * 1024))[tid] = o.v;
    }
    return;
  }

  // ---- GroupNorm, transposed output (was gn_t_kernel) ----
  const int blk = blockIdx.x;
  const int b = blk >> 5, g = blk & 31;
  const float* xp = x + (size_t)(b * 1024 + g * 32) * 1024;

  float s = 0.f, ss = 0.f;
  for (int ch = tid; ch < 4096; ch += 256) {
    const float4* p = (const float4*)(xp + (size_t)ch * 8);
    float4 u0 = p[0], u1 = p[1];
    s  += u0.x + u0.y + u0.z + u0.w + u1.x + u1.y + u1.z + u1.w;
    ss += u0.x*u0.x + u0.y*u0.y + u0.z*u0.z + u0.w*u0.w
        + u1.x*u1.x + u1.y*u1.y + u1.z*u1.z + u1.w*u1.w;
  }
  #pragma unroll
  for (int m = 1; m < 64; m <<= 1) { s += __shfl_xor(s, m); ss += __shfl_xor(ss, m); }

  __shared__ float red[8];
  __shared__ float stats[2];
  const int wave = tid >> 6, lane = tid & 63;
  if (lane == 0) { red[wave] = s; red[4 + wave] = ss; }
  __syncthreads();
  if (tid == 0) {
    float ts  = red[0] + red[1] + red[2] + red[3];
    float tss = red[4] + red[5] + red[6] + red[7];
    float mu  = ts * (1.f / 32768.f);
    float var = tss * (1.f / 32768.f) - mu * mu;
    stats[0] = mu;
    stats[1] = rsqrtf(var + 1e-5f);
  }
  __syncthreads();
  const float mu = stats[0], rs = stats[1];

  for (int ti = 0; ti < 4; ++ti) {
    const int t = ti * 256 + tid;
    B8 o[4];
    #pragma unroll
    for (int cc = 0; cc < 32; ++cc) {
      const float wt = w[g * 32 + cc] * rs;
      const float bsv = bias[g * 32 + cc];
      const float v = xp[(size_t)cc * 1024 + t];
      o[cc >> 3].e[cc & 7] = (bf16)((v - mu) * wt + bsv);
    }
    bf16* dst = xnt + (size_t)(b * 1024 + t) * 1024 + g * 32;
    #pragma unroll
    for (int j = 0; j < 4; ++j) *(bf16x8*)(dst + j * 8) = o[j].v;
  }
}

// ---------------------------------------------------------------------------
// Kernel 2: merged qkv GEMM. Tile 256x192 -> grid 256 blocks = 1/CU.
// Minimal 2-phase pipeline: all ds_reads of the current buffer first, then
// next tile's 7 global_load_lds into buf^1, then 48 MFMAs, one __syncthreads
// per K-tile. 8 waves (2M x 4N), wave tile 128x48. LDS 112 KB.
// Round-6: per-XCD block chunk remapped 2bxn x 16bym -> 8bxn x 4bym:
// per-XCD L2 working set 8.75 MB -> 5 MB (A 2 MB + B 3 MB), raising the
// staging L2 hit rate. Bijective (xcd, c) -> (bym, bxn).
// ---------------------------------------------------------------------------
__global__ __launch_bounds__(512, 2) void gemm_qkv_kernel(
    const bf16* __restrict__ xnt, const bf16* __restrict__ Wb,
    const float* __restrict__ bs, bf16* __restrict__ qkT, bf16* __restrict__ vv)
{
  const int bid = blockIdx.x;
  const int k = bid & 7, c = bid >> 3;           // xcd, chunk index 0..31
  const int bym = (k & 3) * 4 + (c & 3);         // 4 M-panels per XCD
  const int bxn = (k >> 2) * 8 + (c >> 2);       // 8 N-panels per XCD
  const int n0 = bxn * 192, m0 = bym * 256;
  const int head = bxn;

  __shared__ __align__(16) bf16 Al[2][256 * 64];
  __shared__ __align__(16) bf16 Bl[2][192 * 64];

  const int tid  = threadIdx.x;
  const int wave = tid >> 6, lane = tid & 63;
  const int quad = lane >> 4, l15 = lane & 15;
  const int wr = wave >> 2, wc = wave & 3;
  const int lrow = lane >> 3, lp = lane & 7;
  const int sc8 = (lp ^ lrow) << 3;   // pre-swizzled source chunk (elements)

  #define STAGE(bufn, kt) do {                                                \
    _Pragma("unroll")                                                         \
    for (int cc = 0; cc < 4; ++cc)                                            \
      GLOAD_LDS16(xnt + (size_t)(m0 + cc * 64 + wave * 8 + lrow) * 1024 +     \
                      (size_t)(kt) * 64 + sc8,                                \
                  &Al[bufn][(cc * 64 + wave * 8) * 64]);                      \
    _Pragma("unroll")                                                         \
    for (int cc = 0; cc < 3; ++cc)                                            \
      GLOAD_LDS16(Wb + (size_t)(n0 + cc * 64 + wave * 8 + lrow) * 1024 +      \
                      (size_t)(kt) * 64 + sc8,                                \
                  &Bl[bufn][(cc * 64 + wave * 8) * 64]);                      \
  } while (0)

  F4 acc[8][3];
  #pragma unroll
  for (int i = 0; i < 8; ++i)
    #pragma unroll
    for (int j = 0; j < 3; ++j) acc[i][j].v = (f32x4){0.f, 0.f, 0.f, 0.f};

  STAGE(0, 0);
  __syncthreads();

  for (int t = 0; t < 16; ++t) {
    const int cb = t & 1;

    bf16x8 af[2][8], bfr[2][3];
    #pragma unroll
    for (int kk = 0; kk < 2; ++kk) {
      #pragma unroll
      for (int nt = 0; nt < 3; ++nt)
        bfr[kk][nt] = SWZ(Bl[cb], wc * 48 + nt * 16 + l15, kk * 4 + quad);
      #pragma unroll
      for (int mt = 0; mt < 8; ++mt)
        af[kk][mt] = SWZ(Al[cb], wr * 128 + mt * 16 + l15, kk * 4 + quad);
    }

    if (t + 1 < 16) STAGE(cb ^ 1, t + 1);

    #pragma unroll
    for (int kk = 0; kk < 2; ++kk)
      #pragma unroll
      for (int mt = 0; mt < 8; ++mt)
        #pragma unroll
        for (int nt = 0; nt < 3; ++nt)
          acc[mt][nt].v = __builtin_amdgcn_mfma_f32_16x16x32_bf16(
              af[kk][mt], bfr[kk][nt], acc[mt][nt].v, 0, 0, 0);

    __syncthreads();
  }
  #undef STAGE

  const int z  = m0 >> 10;
  const int tb = (m0 & 1023) + wr * 128;
  float bbv[3];
  #pragma unroll
  for (int nt = 0; nt < 3; ++nt) bbv[nt] = bs[n0 + wc * 48 + nt * 16 + l15];

  // q/k columns: nt innermost so the 3 chunks of one row merge (96B burst).
  #pragma unroll
  for (int mt = 0; mt < 8; ++mt)
    #pragma unroll
    for (int r = 0; r < 4; ++r) {
      const int m = m0 + wr * 128 + mt * 16 + quad * 4 + r;
      #pragma unroll
      for (int nt = 0; nt < 3; ++nt) {
        const int r192 = wc * 48 + nt * 16;   // wave-uniform
        if (r192 < 128)
          qkT[(size_t)m * 2048 + head * 128 + r192 + l15] =
              (bf16)(acc[mt][nt].e[r] + bbv[nt]);
      }
    }
  // v rows: original packed form (4 consecutive t per 8B store).
  #pragma unroll
  for (int nt = 0; nt < 3; ++nt) {
    const int r192 = wc * 48 + nt * 16;
    if (r192 >= 128) {
      bf16* vrow = vv + ((size_t)z * 1024 + head * 64 + (r192 - 128) + l15) * 1024;
      #pragma unroll
      for (int mt = 0; mt < 8; ++mt) {
        B4 pk;
        #pragma unroll
        for (int r = 0; r < 4; ++r) pk.e[r] = (bf16)(acc[mt][nt].e[r] + bbv[nt]);
        *(bf16x4*)&vrow[tb + mt * 16 + quad * 4] = pk.v;
      }
    }
  }
}

// ---------------------------------------------------------------------------
// Kernel 4: proj GEMM v3. One GEMM M=1024(ch) x N=4096(b*t) x K=1024, tile
// 128x128, grid 256 = 1/CU, BK=128 (two 64-wide sub-tiles) -> 32 MFMA/wave
// per barrier-pair. LDS 128 KB. out = acc + bias + residual (fp32).
// ---------------------------------------------------------------------------
__global__ __launch_bounds__(512, 2) void gemm_proj_kernel(
    const bf16* __restrict__ Pb, const bf16* __restrict__ Bt,
    float* __restrict__ out, const float* __restrict__ bias,
    const float* __restrict__ resf)
{
  const int bid = blockIdx.x;
  const int swz = (bid & 7) * 32 + (bid >> 3);   // bijective: 256 = 8 * 32
  const int mp = swz & 7, np = swz >> 3;
  const int m0 = mp * 128;                       // channel base
  const int n0g = np * 128;                      // global t base (b*1024+t)

  __shared__ __align__(16) bf16 Al[2][2][128 * 64]; // [buf][k-half][row][64]
  __shared__ __align__(16) bf16 Bl[2][2][128 * 64];

  const int tid  = threadIdx.x;
  const int wave = tid >> 6, lane = tid & 63;
  const int quad = lane >> 4, l15 = lane & 15;
  const int wr = wave >> 2, wc = wave & 3;       // 2(m) x 4(n)
  const int lrow = lane >> 3, lp = lane & 7;
  const int sc8 = (lp ^ lrow) << 3;

  #define STAGE(bufn, kt) do {                                                \
    _Pragma("unroll")                                                         \
    for (int h = 0; h < 2; ++h) {                                             \
      _Pragma("unroll")                                                       \
      for (int cc = 0; cc < 2; ++cc) {                                        \
        GLOAD_LDS16(Pb + (size_t)(m0 + cc * 64 + wave * 8 + lrow) * 1024 +    \
                        (size_t)(kt) * 128 + h * 64 + sc8,                    \
                    &Al[bufn][h][(cc * 64 + wave * 8) * 64]);                 \
        GLOAD_LDS16(Bt + (size_t)(n0g + cc * 64 + wave * 8 + lrow) * 1024 +   \
                        (size_t)(kt) * 128 + h * 64 + sc8,                    \
                    &Bl[bufn][h][(cc * 64 + wave * 8) * 64]);                 \
      }                                                                       \
    }                                                                         \
  } while (0)

  F4 acc[4][2];
  #pragma unroll
  for (int i = 0; i < 4; ++i)
    #pragma unroll
    for (int j = 0; j < 2; ++j) acc[i][j].v = (f32x4){0.f, 0.f, 0.f, 0.f};

  STAGE(0, 0);
  __syncthreads();

  for (int t = 0; t < 8; ++t) {
    const int cb = t & 1;

    bf16x8 af[2][2][4], bfr[2][2][2];
    #pragma unroll
    for (int h = 0; h < 2; ++h)
      #pragma unroll
      for (int kk = 0; kk < 2; ++kk) {
        #pragma unroll
        for (int mt = 0; mt < 4; ++mt)
          af[h][kk][mt] = SWZ(Al[cb][h], wr * 64 + mt * 16 + l15, kk * 4 + quad);
        #pragma unroll
        for (int nt = 0; nt < 2; ++nt)
          bfr[h][kk][nt] = SWZ(Bl[cb][h], wc * 32 + nt * 16 + l15, kk * 4 + quad);
      }

    if (t + 1 < 8) STAGE(cb ^ 1, t + 1);

    #pragma unroll
    for (int h = 0; h < 2; ++h)
      #pragma unroll
      for (int kk = 0; kk < 2; ++kk)
        #pragma unroll
        for (int mt = 0; mt < 4; ++mt)
          #pragma unroll
          for (int nt = 0; nt < 2; ++nt)
            acc[mt][nt].v = __builtin_amdgcn_mfma_f32_16x16x32_bf16(
                af[h][kk][mt], bfr[h][kk][nt], acc[mt][nt].v, 0, 0, 0);

    __syncthreads();
  }
  #undef STAGE

  const int z  = n0g >> 10;                 // block-uniform (128 | 1024)
  const int nl = n0g & 1023;
  const size_t zoff = (size_t)z * 1024 * 1024;
  #pragma unroll
  for (int mt = 0; mt < 4; ++mt) {
    #pragma unroll
    for (int r = 0; r < 4; ++r) {
      const int m = m0 + wr * 64 + mt * 16 + quad * 4 + r;
      const float bb = bias[m];
      #pragma unroll
      for (int nt = 0; nt < 2; ++nt) {
        const int n = nl + wc * 32 + nt * 16 + l15;
        out[zoff + (size_t)m * 1024 + n] =
            acc[mt][nt].e[r] + bb + resf[zoff + (size_t)m * 1024 + n];
      }
    }
  }
}

// ---------------------------------------------------------------------------
// Kernel 3: attention v2. QBLK 256: 8 waves, grid (16,4,4) = 256 blocks =
// 1/CU. Each wave owns 2 independent 16-t bands; k/v staged 8 rows/wave,
// double-buffered; ds-reads-first ordering. LDS 64 KB.
// ---------------------------------------------------------------------------
__global__ __launch_bounds__(512) void attn_kernel(
    const bf16* __restrict__ qkTin, const bf16* __restrict__ vmat,
    bf16* __restrict__ aout)
{
  const int h = blockIdx.x, tt = blockIdx.y, z = blockIdx.z;
  const bf16* qk = qkTin + (size_t)z * 1024 * 2048;
  const bf16* vp = vmat + (size_t)z * 1024 * 1024 + (size_t)(h * 64) * 1024;
  aout += (size_t)z * 1024 * 1024;
  const int t0 = tt * 256;

  __shared__ __align__(16) bf16 qP[256 * 64];     // q rows (init) then P bands
  __shared__ __align__(16) bf16 kl[2][64 * 64];
  __shared__ __align__(16) bf16 vl[2][64 * 64];

  const int tid  = threadIdx.x;
  const int wave = tid >> 6, lane = tid & 63;     // wave 0..7
  const int quad = lane >> 4, l15 = lane & 15;
  const int lrow = lane >> 3, lp = lane & 7;

  #pragma unroll
  for (int c = 0; c < 4; ++c) {
    const int row = wave * 32 + c * 8 + lrow;
    const int c8  = lp ^ (row & 7);
    GLOAD_LDS16(qk + (size_t)(t0 + row) * 2048 + h * 128 + c8 * 8,
                &qP[(wave * 32 + c * 8) * 64]);
  }
  const int r0 = wave * 8 + lrow;                 // 0..63
  const int c80 = lp ^ (r0 & 7);                  // = lp ^ lrow
  GLOAD_LDS16(qk + (size_t)r0 * 2048 + h * 128 + 64 + c80 * 8, &kl[0][(wave * 8) * 64]);
  GLOAD_LDS16(vp + (size_t)r0 * 1024 + c80 * 8, &vl[0][(wave * 8) * 64]);
  __syncthreads();

  bf16x8 bq0[2], bq1[2];
  int prow[2];
  #pragma unroll
  for (int b = 0; b < 2; ++b) {
    const int Rq = wave * 32 + b * 16 + l15;
    bq0[b] = SWZ(qP, Rq, quad);
    bq1[b] = SWZ(qP, Rq, quad + 4);
    prow[b] = Rq;
  }

  float l_i[2] = {0.f, 0.f};
  F4 oacc[2][4];
  #pragma unroll
  for (int b = 0; b < 2; ++b)
    #pragma unroll
    for (int ct = 0; ct < 4; ++ct) oacc[b][ct].v = (f32x4){0.f, 0.f, 0.f, 0.f};

  const int pq8 = (quad & 1) * 4;

  int buf = 0;
  for (int s0 = 0; s0 < 1024; s0 += 64) {
    // 1) Band-invariant k and v fragments: read FIRST (ds-reads-first recipe).
    bf16x8 ak0[4], ak1[4], bv[2][4];
    #pragma unroll
    for (int st = 0; st < 4; ++st) {
      const int Rk = st * 16 + l15;
      ak0[st] = SWZ(kl[buf], Rk, quad);
      ak1[st] = SWZ(kl[buf], Rk, quad + 4);
    }
    #pragma unroll
    for (int ks = 0; ks < 2; ++ks)
      #pragma unroll
      for (int ct = 0; ct < 4; ++ct)
        bv[ks][ct] = SWZ(vl[buf], ct * 16 + l15, ks * 4 + quad);

    // 2) Prefetch next chunk (2 DMA calls per wave).
    if (s0 + 64 < 1024) {
      const int nb = buf ^ 1, sn = s0 + 64;
      GLOAD_LDS16(qk + (size_t)(sn + r0) * 2048 + h * 128 + 64 + c80 * 8,
                  &kl[nb][(wave * 8) * 64]);
      GLOAD_LDS16(vp + (size_t)r0 * 1024 + sn + c80 * 8, &vl[nb][(wave * 8) * 64]);
    }

    // 3) Two bands: QK^T -> exp -> P (LDS round-trip) -> PV.
    #pragma unroll
    for (int b = 0; b < 2; ++b) {
      F4 sacc[4];
      #pragma unroll
      for (int st = 0; st < 4; ++st) sacc[st].v = (f32x4){0.f, 0.f, 0.f, 0.f};
      #pragma unroll
      for (int st = 0; st < 4; ++st) {
        sacc[st].v = __builtin_amdgcn_mfma_f32_16x16x32_bf16(ak0[st], bq0[b], sacc[st].v, 0, 0, 0);
        sacc[st].v = __builtin_amdgcn_mfma_f32_16x16x32_bf16(ak1[st], bq1[b], sacc[st].v, 0, 0, 0);
      }

      bf16* const pbase = &qP[(size_t)prow[b] * 64];
      #pragma unroll
      for (int st = 0; st < 4; ++st) {
        B4 pk;
        #pragma unroll
        for (int r = 0; r < 4; ++r) {
          const float p = __builtin_amdgcn_exp2f(sacc[st].e[r]);
          l_i[b] += p;
          pk.e[r] = (bf16)p;
        }
        const int c8 = (st * 2 + (quad >> 1)) ^ (prow[b] & 7);
        *(bf16x4*)(pbase + (c8 << 3) + pq8) = pk.v;
      }

      #pragma unroll
      for (int ks = 0; ks < 2; ++ks) {
        const bf16x8 ap = SWZ(qP, prow[b], ks * 4 + quad);
        #pragma unroll
        for (int ct = 0; ct < 4; ++ct)
          oacc[b][ct].v = __builtin_amdgcn_mfma_f32_16x16x32_bf16(
              ap, bv[ks][ct], oacc[b][ct].v, 0, 0, 0);
      }
    }
    __syncthreads();   // drains next-chunk DMA; all waves done with buf
    buf ^= 1;
  }

  #pragma unroll
  for (int b = 0; b < 2; ++b) {
    float li = l_i[b];
    li += __shfl_xor(li, 16);
    li += __shfl_xor(li, 32);
    const float inv = 1.f / li;
    float iv[4];
    #pragma unroll
    for (int r = 0; r < 4; ++r) iv[r] = __shfl(inv, quad * 4 + r);
    #pragma unroll
    for (int r = 0; r < 4; ++r) {
      const int t = t0 + wave * 32 + b * 16 + quad * 4 + r;
      #pragma unroll
      for (int ct = 0; ct < 4; ++ct)
        aout[(size_t)t * 1024 + h * 64 + ct * 16 + l15] = (bf16)(oacc[b][ct].e[r] * iv[r]);
    }
  }
}

// ---------------------------------------------------------------------------
// ws layout:
//   xnt [b][t][c] : ws[ 0,  8 MB)
//   qkT [b][t][n] : ws[ 8, 24 MB)
//   v   [b][ov][t]: ws[24, 32 MB)
//   a^T [b][t][c] : ws[32, 40 MB)
//   Wb / Pb / bs  : ws[40, 48 MB) + 12 KB
// ---------------------------------------------------------------------------
extern "C" void kernel_launch(void* const* d_in, const int* in_sizes, int n_in,
                              void* d_out, int out_size, void* d_ws, size_t ws_size,
                              hipStream_t stream)
{
  const float* x    = (const float*)d_in[0];
  const float* nw   = (const float*)d_in[1];
  const float* nb   = (const float*)d_in[2];
  const float* qkvw = (const float*)d_in[3];
  const float* qkvb = (const float*)d_in[4];
  const float* pw   = (const float*)d_in[5];
  const float* pb   = (const float*)d_in[6];
  float* out = (float*)d_out;

  const long M1 = 1024L * 1024L;
  bf16*  xnt = (bf16*)d_ws;
  bf16*  qkT = xnt + 4 * M1;
  bf16*  vv  = xnt + 12 * M1;
  bf16*  at  = xnt + 16 * M1;
  bf16*  Wb  = xnt + 20 * M1;
  bf16*  Pb  = xnt + 23 * M1;
  float* bs  = (float*)(xnt + 24 * M1);

  pre_kernel<<<dim3(4224), dim3(256), 0, stream>>>(x, nw, nb, xnt,
                                                   qkvw, qkvb, pw, Wb, Pb, bs);
  gemm_qkv_kernel<<<dim3(256), dim3(512), 0, stream>>>(xnt, Wb, bs, qkT, vv);
  attn_kernel<<<dim3(16, 4, 4), dim3(512), 0, stream>>>(qkT, vv, at);
  gemm_proj_kernel<<<dim3(256), dim3(512), 0, stream>>>(Pb, at, out, pb, x);
}